// Round 6
// baseline (230.032 us; speedup 1.0000x reference)
//
#include <hip/hip_runtime.h>
#include <math.h>

// ---------------------------------------------------------------------------
// mLSTM cell, MFMA bf16. Round 6: k_attn with depth-ADJACENT block pairing
// (both co-resident blocks on a CU live equally long and interleave), K, V
// and a[t] all register-prefetched one k-tile ahead (no vmem waits on the
// per-tile critical path), W double-buffered in LDS -> ONE lgkm-only barrier
// per tile. Numerics identical to rounds 3-5.
// ---------------------------------------------------------------------------

#define BB   2
#define SS   2048
#define DD   1024
#define NHH  4
#define DHH  256
#define BHH  (BB*NHH)

// Workspace byte offsets (total ~32.5 MB)
#define QB_OFF   ((size_t)0)
#define KB_OFF   ((size_t)8  << 20)
#define VT_OFF   ((size_t)16 << 20)
#define VB_OFF   ((size_t)24 << 20)
#define IG_OFF   ((size_t)32 << 20)
#define LSF_OFF  (IG_OFF  + ((size_t)64<<10))
#define AA_OFF   (LSF_OFF + ((size_t)64<<10))
#define MM_OFF   (AA_OFF  + ((size_t)64<<10))
#define FLR_OFF  (MM_OFF  + ((size_t)64<<10))
#define WSI_OFF  (FLR_OFF + ((size_t)64<<10))
#define WSF_OFF  (WSI_OFF + ((size_t)32<<10))

typedef __attribute__((ext_vector_type(8))) short short8;   // 8 bf16 (4 VGPR)
typedef __attribute__((ext_vector_type(4))) float f32x4;

__device__ __forceinline__ unsigned short f2b(float f) {
  union { float f; unsigned int u; } v; v.f = f;
  unsigned int r = (v.u + 0x7FFFu + ((v.u >> 16) & 1u)) >> 16;
  return (unsigned short)r;
}

// ---------------------------------------------------------------------------
// Kernel 0: gate weight pre-sum: wsum[n][c] = sum of 3 D-segments.
// ---------------------------------------------------------------------------
__global__ __launch_bounds__(256) void k_gw(
    const float* __restrict__ wi, const float* __restrict__ wf,
    float* __restrict__ wsi, float* __restrict__ wsf)
{
  const int idx = blockIdx.x*256 + threadIdx.x;   // 0..8191
  const int n = idx >> 10, c = idx & 1023;
  wsi[idx] = wi[n*3*DD + c] + wi[n*3*DD + DD + c] + wi[n*3*DD + 2*DD + c];
  wsf[idx] = wf[n*3*DD + c] + wf[n*3*DD + DD + c] + wf[n*3*DD + 2*DD + c];
}

// ---------------------------------------------------------------------------
// Kernel 1: headwise QKV projection (4x4 blocks) + gate GEMVs. bf16 outputs.
// ---------------------------------------------------------------------------
__global__ __launch_bounds__(256) void k_proj(
    const float* __restrict__ x,
    const float* __restrict__ wq, const float* __restrict__ wk, const float* __restrict__ wv,
    const float* __restrict__ wsi, const float* __restrict__ bi,
    const float* __restrict__ wsf, const float* __restrict__ bf,
    unsigned short* __restrict__ qb, unsigned short* __restrict__ kb,
    unsigned short* __restrict__ vb, float* __restrict__ ig, float* __restrict__ lsf)
{
  const int row = blockIdx.x;          // b*SS + s
  const int b   = row >> 11;
  const int s   = row & (SS-1);
  const int g   = threadIdx.x;         // qkv head 0..255

  const float4 xv = *(const float4*)(x + (size_t)row*DD + (g<<2));

  const int h   = g >> 6;
  const int dh0 = (g & 63) << 2;
  const size_t qi = ((size_t)(b*NHH + h)*SS + s)*DHH + dh0;

  {
    const float4 w0 = *(const float4*)(wq + g*16 + 0);
    const float4 w1 = *(const float4*)(wq + g*16 + 4);
    const float4 w2 = *(const float4*)(wq + g*16 + 8);
    const float4 w3 = *(const float4*)(wq + g*16 + 12);
    ushort4 r;
    r.x = f2b(w0.x*xv.x + w0.y*xv.y + w0.z*xv.z + w0.w*xv.w);
    r.y = f2b(w1.x*xv.x + w1.y*xv.y + w1.z*xv.z + w1.w*xv.w);
    r.z = f2b(w2.x*xv.x + w2.y*xv.y + w2.z*xv.z + w2.w*xv.w);
    r.w = f2b(w3.x*xv.x + w3.y*xv.y + w3.z*xv.z + w3.w*xv.w);
    *(ushort4*)(qb + qi) = r;
  }
  {
    const float4 w0 = *(const float4*)(wk + g*16 + 0);
    const float4 w1 = *(const float4*)(wk + g*16 + 4);
    const float4 w2 = *(const float4*)(wk + g*16 + 8);
    const float4 w3 = *(const float4*)(wk + g*16 + 12);
    ushort4 r;
    r.x = f2b(0.0625f*(w0.x*xv.x + w0.y*xv.y + w0.z*xv.z + w0.w*xv.w));
    r.y = f2b(0.0625f*(w1.x*xv.x + w1.y*xv.y + w1.z*xv.z + w1.w*xv.w));
    r.z = f2b(0.0625f*(w2.x*xv.x + w2.y*xv.y + w2.z*xv.z + w2.w*xv.w));
    r.w = f2b(0.0625f*(w3.x*xv.x + w3.y*xv.y + w3.z*xv.z + w3.w*xv.w));
    *(ushort4*)(kb + qi) = r;
  }
  {
    const float4 w0 = *(const float4*)(wv + g*16 + 0);
    const float4 w1 = *(const float4*)(wv + g*16 + 4);
    const float4 w2 = *(const float4*)(wv + g*16 + 8);
    const float4 w3 = *(const float4*)(wv + g*16 + 12);
    ushort4 r;
    r.x = f2b(w0.x*xv.x + w0.y*xv.y + w0.z*xv.z + w0.w*xv.w);
    r.y = f2b(w1.x*xv.x + w1.y*xv.y + w1.z*xv.z + w1.w*xv.w);
    r.z = f2b(w2.x*xv.x + w2.y*xv.y + w2.z*xv.z + w2.w*xv.w);
    r.w = f2b(w3.x*xv.x + w3.y*xv.y + w3.z*xv.z + w3.w*xv.w);
    *(ushort4*)(vb + qi) = r;
  }

  float pi[4], pf[4];
  const int c = g << 2;
  #pragma unroll
  for (int n=0;n<4;n++) {
    const float4 a0 = *(const float4*)(wsi + n*DD + c);
    pi[n] = a0.x*xv.x + a0.y*xv.y + a0.z*xv.z + a0.w*xv.w;
    const float4 b0 = *(const float4*)(wsf + n*DD + c);
    pf[n] = b0.x*xv.x + b0.y*xv.y + b0.z*xv.z + b0.w*xv.w;
  }
  #pragma unroll
  for (int off=32; off>0; off>>=1) {
    #pragma unroll
    for (int n=0;n<4;n++) {
      pi[n] += __shfl_down(pi[n], off);
      pf[n] += __shfl_down(pf[n], off);
    }
  }
  __shared__ float red[4][8];
  const int lane = g & 63, wid = g >> 6;
  if (lane == 0) {
    #pragma unroll
    for (int n=0;n<4;n++) { red[wid][n] = pi[n]; red[wid][4+n] = pf[n]; }
  }
  __syncthreads();
  if (g < 4) {
    const int n = g;
    float ti = red[0][n]+red[1][n]+red[2][n]+red[3][n] + bi[n];
    float tf = red[0][4+n]+red[1][4+n]+red[2][4+n]+red[3][4+n] + bf[n];
    ig[(size_t)(b*NHH+n)*SS + s] = ti;
    float ls = (tf >= 0.f) ? -log1pf(expf(-tf)) : (tf - log1pf(expf(tf)));
    lsf[(size_t)(b*NHH+n)*SS + s] = ls;
  }
}

// ---------------------------------------------------------------------------
// Kernel 2: per-(b,head) scan.
// ---------------------------------------------------------------------------
__global__ __launch_bounds__(256) void k_scan(
    const float* __restrict__ ig, const float* __restrict__ lsf,
    float* __restrict__ aa, float* __restrict__ mm, float* __restrict__ flr)
{
  const int bh = blockIdx.x;
  const int tid = threadIdx.x;
  const float* igp = ig + (size_t)bh*SS;
  const float* lsp = lsf + (size_t)bh*SS;
  float* ap = aa + (size_t)bh*SS;
  float* mp = mm + (size_t)bh*SS;
  float* fp = flr + (size_t)bh*SS;

  __shared__ float sb[256];
  const int base = tid*8;
  float l[8], c[8];
  #pragma unroll
  for (int j=0;j<8;j++) l[j] = lsp[base+j];
  c[0] = l[0];
  #pragma unroll
  for (int j=1;j<8;j++) c[j] = c[j-1] + l[j];

  sb[tid] = c[7];
  __syncthreads();
  for (int off=1; off<256; off<<=1) {
    float v = sb[tid];
    float u = (tid>=off) ? sb[tid-off] : 0.f;
    __syncthreads();
    sb[tid] = v + u;
    __syncthreads();
  }
  const float exs = (tid==0) ? 0.f : sb[tid-1];

  float cs[8], a8[8], mx[8];
  #pragma unroll
  for (int j=0;j<8;j++) { cs[j] = exs + c[j]; a8[j] = igp[base+j] - cs[j]; }
  mx[0] = a8[0];
  #pragma unroll
  for (int j=1;j<8;j++) mx[j] = fmaxf(mx[j-1], a8[j]);

  __syncthreads();
  sb[tid] = mx[7];
  __syncthreads();
  for (int off=1; off<256; off<<=1) {
    float v = sb[tid];
    float u = (tid>=off) ? sb[tid-off] : -INFINITY;
    __syncthreads();
    sb[tid] = fmaxf(v, u);
    __syncthreads();
  }
  const float exm = (tid==0) ? -INFINITY : sb[tid-1];

  #pragma unroll
  for (int j=0;j<8;j++) {
    float mmx = fmaxf(exm, mx[j]);
    ap[base+j] = a8[j];
    mp[base+j] = mmx;
    fp[base+j] = expf(-(cs[j] + mmx));
  }
}

// ---------------------------------------------------------------------------
// Kernel 3: transpose V bf16 [bh][s][d] -> Vt [bh][d][s].
// ---------------------------------------------------------------------------
__global__ __launch_bounds__(256) void k_vt(
    const unsigned short* __restrict__ vb, unsigned short* __restrict__ vt)
{
  __shared__ unsigned short tile[64][72];
  const int bh = blockIdx.x, st = blockIdx.y, dt = blockIdx.z;
  const int s0 = st*64, d0 = dt*64;
  const unsigned short* src = vb + ((size_t)bh*SS + s0)*DHH + d0;
  #pragma unroll
  for (int j=0;j<2;j++){
    int f = threadIdx.x + j*256;           // 0..511
    int r = f>>3, c = (f&7)*8;
    *(uint4*)&tile[r][c] = *(const uint4*)(src + (size_t)r*DHH + c);
  }
  __syncthreads();
  unsigned short* dst = vt + ((size_t)bh*DHH + d0)*SS + s0;
  #pragma unroll
  for (int j=0;j<2;j++){
    int f = threadIdx.x + j*256;
    int dr = f>>3, sc = (f&7)*8;
    unsigned short tmp[8];
    #pragma unroll
    for (int i=0;i<8;i++) tmp[i] = tile[sc+i][dr];
    *(uint4*)(dst + (size_t)dr*SS + sc) = *(uint4*)tmp;
  }
}

// ---------------------------------------------------------------------------
// Kernel 4: MFMA attention, fully prefetched, depth-adjacent pairing.
// 512 blocks = 8 bh (XCD pin via bid&7) x 64 q-tiles of 32 rows.
// rt map: j<32 -> 2j (even tiles), j>=32 -> 2(j-32)+1 (odd tiles): co-resident
// blocks (j, j+32) or (2i, 2i+1) have ADJACENT depths -> both live the whole
// kernel and interleave, halving effective per-tile latency.
// Per tile: QK(MFMA, K prefetched) -> prefetch K/V/a (kt+1) -> W phase ->
// lgkmcnt(0) + s_barrier (ONE barrier; W double-buffered) -> PV(MFMA, V
// prefetched). No vmem waits on the critical path.
// ---------------------------------------------------------------------------
__global__ __launch_bounds__(256, 2) void k_attn(
    const unsigned short* __restrict__ qb, const unsigned short* __restrict__ kb,
    const unsigned short* __restrict__ vt,
    const float* __restrict__ ab, const float* __restrict__ mb,
    const float* __restrict__ flr, const float* __restrict__ ln_w,
    float* __restrict__ out)
{
  __shared__ __align__(16) char smWb[2*32*128];   // W dbuf: 2 x 32 rows x 128B
  __shared__ float smRed[32*4];
  __shared__ float smS1[32*4];
  __shared__ float smS2[32*4];

  const int bid = blockIdx.x;
  const int bh  = bid & 7;                 // XCD pin
  const int j   = bid >> 3;                // 0..63
  const int rt  = (j < 32) ? (2*j) : (2*(j-32) + 1);
  const int s0  = rt * 32;
  const int nkt = (32*rt + 95) >> 6;       // ceil((s0+32)/64), 1..32

  const int tid  = threadIdx.x;
  const int lane = tid & 63;
  const int w    = tid >> 6;               // wave 0..3
  const int l15  = lane & 15, lg = lane >> 4;
  const int bhoff = bh * SS;
  const int b = bh >> 2, h = bh & 3;

  const char* kbh = (const char*)(kb + (size_t)bh*SS*DHH);   // rows of 512B
  const char* vth = (const char*)(vt + (size_t)bh*DHH*SS);   // d-rows of 4096B

  // Q register-resident: 32 rows (mt bands of 16)
  short8 qf[2][8];
  {
    const unsigned short* qp = qb + ((size_t)bh*SS + s0)*DHH;
    #pragma unroll
    for (int mt=0; mt<2; ++mt)
      #pragma unroll
      for (int ks=0; ks<8; ++ks)
        qf[mt][ks] = *(const short8*)(qp + (16*mt + l15)*DHH + 32*ks + 8*lg);
  }
  float mrow[2][4];
  #pragma unroll
  for (int mt=0; mt<2; ++mt)
    #pragma unroll
    for (int rr=0; rr<4; ++rr)
      mrow[mt][rr] = mb[bhoff + s0 + 16*mt + 4*lg + rr];

  f32x4 oacc[2][4];
  #pragma unroll
  for (int mt=0; mt<2; ++mt)
    #pragma unroll
    for (int nt=0; nt<4; ++nt)
      oacc[mt][nt] = (f32x4){0.f,0.f,0.f,0.f};
  float denp[2][4] = {{0.f,0.f,0.f,0.f},{0.f,0.f,0.f,0.f}};

  const int trel = 16*w + l15;             // QKT col within k-tile, 0..63

  short8 kA[8], kB[8], vA[8], vB[8];
  float avC;

  // prologue: K(0) -> kA, V(0) -> vA, av(0)
  {
    const char* kp = kbh + (size_t)trel*512 + lg*16;
    #pragma unroll
    for (int ks=0; ks<8; ++ks) kA[ks] = *(const short8*)(kp + ks*64);
    const char* vp = vth + lg*16;
    #pragma unroll
    for (int i=0;i<8;++i) {
      const int d = 64*w + 16*(i&3) + l15;
      vA[i] = *(const short8*)(vp + (size_t)d*4096 + (i>>2)*64);
    }
    avC = ab[bhoff + trel];
  }

#define TILE_BODY(KC, KN, VC, VN)                                              \
  do {                                                                         \
    const int t0 = kt*64;                                                      \
    /* QK^T from KC (prefetched one tile ago) */                               \
    f32x4 sA = (f32x4){0.f,0.f,0.f,0.f};                                       \
    f32x4 sB = (f32x4){0.f,0.f,0.f,0.f};                                       \
    __builtin_amdgcn_s_setprio(1);                                             \
    _Pragma("unroll")                                                          \
    for (int ks=0; ks<8; ++ks) {                                               \
      sA = __builtin_amdgcn_mfma_f32_16x16x32_bf16(qf[0][ks], KC[ks], sA, 0,0,0); \
      sB = __builtin_amdgcn_mfma_f32_16x16x32_bf16(qf[1][ks], KC[ks], sB, 0,0,0); \
    }                                                                          \
    __builtin_amdgcn_s_setprio(0);                                             \
    /* prefetch tile kt+1: K first (next QK waits only K; V flies to PV) */    \
    float avN = 0.f;                                                           \
    if (kt+1 < nkt) {                                                          \
      const char* kp = kbh + (size_t)(t0 + 64 + trel)*512 + lg*16;             \
      _Pragma("unroll")                                                        \
      for (int ks=0; ks<8; ++ks) KN[ks] = *(const short8*)(kp + ks*64);        \
      const char* vp = vth + (size_t)(t0 + 64)*2 + lg*16;                      \
      _Pragma("unroll")                                                        \
      for (int i=0;i<8;++i) {                                                  \
        const int d = 64*w + 16*(i&3) + l15;                                   \
        VN[i] = *(const short8*)(vp + (size_t)d*4096 + (i>>2)*64);             \
      }                                                                        \
      avN = ab[bhoff + t0 + 64 + trel];                                       \
    }                                                                          \
    /* W = mask * qk * exp(a[t]-m[s]) -> bf16 into W[kt&1] (swizzled) */       \
    {                                                                          \
      char* smW = smWb + ((kt&1)<<12);                                         \
      const bool lastt = (kt == nkt-1);                                        \
      _Pragma("unroll")                                                        \
      for (int mt=0; mt<2; ++mt) {                                             \
        _Pragma("unroll")                                                      \
        for (int rr=0; rr<4; ++rr) {                                           \
          const int srel = 16*mt + 4*lg + rr;                                  \
          float wv = (mt ? sB[rr] : sA[rr]) * __expf(avC - mrow[mt][rr]);      \
          if (lastt && (t0 + trel > s0 + srel)) wv = 0.f;                      \
          denp[mt][rr] += wv;                                                  \
          *(unsigned short*)(smW + (size_t)srel*128 +                          \
              (((trel >> 3) ^ (srel & 7))<<4) + ((trel & 7)<<1)) = f2b(wv);    \
        }                                                                      \
      }                                                                        \
    }                                                                          \
    avC = avN;                                                                 \
    asm volatile("s_waitcnt lgkmcnt(0)" ::: "memory");                         \
    __builtin_amdgcn_s_barrier();                                              \
    asm volatile("" ::: "memory");                                             \
    /* PV: oacc += W[kt&1] @ VC */                                             \
    {                                                                          \
      const char* smW = smWb + ((kt&1)<<12);                                   \
      _Pragma("unroll")                                                        \
      for (int kst=0; kst<2; ++kst) {                                          \
        short8 wf0, wf1;                                                       \
        { const int sr = l15;                                                  \
          wf0 = *(const short8*)(smW + (size_t)sr*128 + (((4*kst+lg)^(sr&7))<<4)); } \
        { const int sr = 16 + l15;                                             \
          wf1 = *(const short8*)(smW + (size_t)sr*128 + (((4*kst+lg)^(sr&7))<<4)); } \
        __builtin_amdgcn_s_setprio(1);                                         \
        _Pragma("unroll")                                                      \
        for (int nt=0; nt<4; ++nt) {                                           \
          oacc[0][nt] = __builtin_amdgcn_mfma_f32_16x16x32_bf16(wf0, VC[kst*4+nt], oacc[0][nt], 0,0,0); \
          oacc[1][nt] = __builtin_amdgcn_mfma_f32_16x16x32_bf16(wf1, VC[kst*4+nt], oacc[1][nt], 0,0,0); \
        }                                                                      \
        __builtin_amdgcn_s_setprio(0);                                         \
      }                                                                        \
    }                                                                          \
  } while(0)

  {
    int kt = 0;
    while (kt < nkt) {
      TILE_BODY(kA, kB, vA, vB);
      ++kt;
      if (kt >= nkt) break;
      TILE_BODY(kB, kA, vB, vA);
      ++kt;
    }
  }
#undef TILE_BODY

  // ---- epilogue: den reduce (lanes then waves), normalizer, LN, write ----
  #pragma unroll
  for (int mt=0; mt<2; ++mt)
    #pragma unroll
    for (int rr=0; rr<4; ++rr) {
      float v = denp[mt][rr];
      v += __shfl_xor(v, 1); v += __shfl_xor(v, 2);
      v += __shfl_xor(v, 4); v += __shfl_xor(v, 8);
      if (l15 == 0) smRed[(16*mt + 4*lg + rr)*4 + w] = v;
    }
  __syncthreads();

  float inv[2][4];
  #pragma unroll
  for (int mt=0; mt<2; ++mt)
    #pragma unroll
    for (int rr=0; rr<4; ++rr) {
      const int srel = 16*mt + 4*lg + rr;
      float dsum = smRed[srel*4+0] + smRed[srel*4+1] + smRed[srel*4+2] + smRed[srel*4+3];
      float f = flr[bhoff + s0 + srel];
      inv[mt][rr] = 1.f / (fmaxf(fabsf(dsum), f) + 1e-8f);
    }

  float s1p[2][4] = {{0,0,0,0},{0,0,0,0}}, s2p[2][4] = {{0,0,0,0},{0,0,0,0}};
  #pragma unroll
  for (int mt=0; mt<2; ++mt)
    #pragma unroll
    for (int nt=0; nt<4; ++nt)
      #pragma unroll
      for (int rr=0; rr<4; ++rr) {
        float v = oacc[mt][nt][rr] * inv[mt][rr];
        oacc[mt][nt][rr] = v;
        s1p[mt][rr] += v;
        s2p[mt][rr] += v*v;
      }
  #pragma unroll
  for (int mt=0; mt<2; ++mt)
    #pragma unroll
    for (int rr=0; rr<4; ++rr) {
      float a = s1p[mt][rr], q = s2p[mt][rr];
      a += __shfl_xor(a, 1); a += __shfl_xor(a, 2);
      a += __shfl_xor(a, 4); a += __shfl_xor(a, 8);
      q += __shfl_xor(q, 1); q += __shfl_xor(q, 2);
      q += __shfl_xor(q, 4); q += __shfl_xor(q, 8);
      if (l15 == 0) {
        const int srel = 16*mt + 4*lg + rr;
        smS1[srel*4 + w] = a;
        smS2[srel*4 + w] = q;
      }
    }
  __syncthreads();

  float g4[4];
  #pragma unroll
  for (int nt=0; nt<4; ++nt) g4[nt] = 1.f + ln_w[h*DHH + 64*w + 16*nt + l15];

  #pragma unroll
  for (int mt=0; mt<2; ++mt)
    #pragma unroll
    for (int rr=0; rr<4; ++rr) {
      const int srel = 16*mt + 4*lg + rr;
      const float ms = smS1[srel*4+0] + smS1[srel*4+1] + smS1[srel*4+2] + smS1[srel*4+3];
      const float sq = smS2[srel*4+0] + smS2[srel*4+1] + smS2[srel*4+2] + smS2[srel*4+3];
      const float mean = ms * (1.f/DHH);
      const float var  = sq * (1.f/DHH) - mean*mean;
      const float rstd = rsqrtf(var + 1e-5f);
      float* op = out + ((size_t)(b*SS + s0 + srel))*DD + h*DHH;
      #pragma unroll
      for (int nt=0; nt<4; ++nt)
        op[64*w + 16*nt + l15] = (oacc[mt][nt][rr] - mean)*rstd*g4[nt];
    }
}

// ---------------------------------------------------------------------------
extern "C" void kernel_launch(void* const* d_in, const int* in_sizes, int n_in,
                              void* d_out, int out_size, void* d_ws, size_t ws_size,
                              hipStream_t stream) {
  (void)in_sizes; (void)n_in; (void)out_size; (void)ws_size;
  const float* x    = (const float*)d_in[0];
  const float* wq   = (const float*)d_in[1];
  const float* wk   = (const float*)d_in[2];
  const float* wv   = (const float*)d_in[3];
  const float* wi   = (const float*)d_in[4];
  const float* bi   = (const float*)d_in[5];
  const float* wf   = (const float*)d_in[6];
  const float* bf   = (const float*)d_in[7];
  const float* ln_w = (const float*)d_in[8];
  float* out = (float*)d_out;
  char* ws = (char*)d_ws;

  unsigned short* QB = (unsigned short*)(ws + QB_OFF);
  unsigned short* KB = (unsigned short*)(ws + KB_OFF);
  unsigned short* VT = (unsigned short*)(ws + VT_OFF);
  unsigned short* VB = (unsigned short*)(ws + VB_OFF);
  float* IG  = (float*)(ws + IG_OFF);
  float* LSF = (float*)(ws + LSF_OFF);
  float* AA  = (float*)(ws + AA_OFF);
  float* MM  = (float*)(ws + MM_OFF);
  float* FLR = (float*)(ws + FLR_OFF);
  float* WSI = (float*)(ws + WSI_OFF);
  float* WSF = (float*)(ws + WSF_OFF);

  k_gw<<<32, 256, 0, stream>>>(wi, wf, WSI, WSF);
  k_proj<<<BB*SS, 256, 0, stream>>>(x, wq, wk, wv, WSI, bi, WSF, bf, QB, KB, VB, IG, LSF);
  k_scan<<<BHH, 256, 0, stream>>>(IG, LSF, AA, MM, FLR);
  k_vt<<<dim3(BHH, SS/64, DHH/64), 256, 0, stream>>>(VB, VT);
  k_attn<<<512, 256, 0, stream>>>(QB, KB, VT, AA, MM, FLR, ln_w, out);
}

// Round 7
// 98.722 us; speedup vs baseline: 2.3301x; 2.3301x over previous
//
#include <hip/hip_runtime.h>
#include <math.h>

// ---------------------------------------------------------------------------
// mLSTM cell, MFMA bf16. Round 7: round-3 geometry (256 blocks, 64-row
// q-tiles, 8 waves, global_load_lds staging, validated swizzles/epilogue)
// + counted-vmcnt 3-barrier pipeline (T3/T4): stage(kt+1) issued at iter top,
// s_waitcnt vmcnt(9) (NOT 0) before the consume barrier -> staged loads stay
// in flight across barriers. All barriers lgkm-only. setprio on MFMA.
// ---------------------------------------------------------------------------

#define BB   2
#define SS   2048
#define DD   1024
#define NHH  4
#define DHH  256
#define BHH  (BB*NHH)

// Workspace byte offsets (total ~32.5 MB)
#define QB_OFF   ((size_t)0)
#define KB_OFF   ((size_t)8  << 20)
#define VT_OFF   ((size_t)16 << 20)
#define VB_OFF   ((size_t)24 << 20)
#define IG_OFF   ((size_t)32 << 20)
#define LSF_OFF  (IG_OFF  + ((size_t)64<<10))
#define AA_OFF   (LSF_OFF + ((size_t)64<<10))
#define MM_OFF   (AA_OFF  + ((size_t)64<<10))
#define FLR_OFF  (MM_OFF  + ((size_t)64<<10))
#define WSI_OFF  (FLR_OFF + ((size_t)64<<10))
#define WSF_OFF  (WSI_OFF + ((size_t)32<<10))

typedef __attribute__((ext_vector_type(8))) short short8;   // 8 bf16 (4 VGPR)
typedef __attribute__((ext_vector_type(4))) float f32x4;

typedef const __attribute__((address_space(1))) unsigned int* gas1_u32;
typedef __attribute__((address_space(3))) unsigned int* las3_u32;

__device__ __forceinline__ unsigned short f2b(float f) {
  union { float f; unsigned int u; } v; v.f = f;
  unsigned int r = (v.u + 0x7FFFu + ((v.u >> 16) & 1u)) >> 16;
  return (unsigned short)r;
}

__device__ __forceinline__ void gload_lds16(void* lds, const void* g) {
  __builtin_amdgcn_global_load_lds((gas1_u32)g, (las3_u32)lds, 16, 0, 0);
}

// ---------------------------------------------------------------------------
// Kernel 0: gate weight pre-sum: wsum[n][c] = sum of 3 D-segments.
// ---------------------------------------------------------------------------
__global__ __launch_bounds__(256) void k_gw(
    const float* __restrict__ wi, const float* __restrict__ wf,
    float* __restrict__ wsi, float* __restrict__ wsf)
{
  const int idx = blockIdx.x*256 + threadIdx.x;   // 0..8191
  const int n = idx >> 10, c = idx & 1023;
  wsi[idx] = wi[n*3*DD + c] + wi[n*3*DD + DD + c] + wi[n*3*DD + 2*DD + c];
  wsf[idx] = wf[n*3*DD + c] + wf[n*3*DD + DD + c] + wf[n*3*DD + 2*DD + c];
}

// ---------------------------------------------------------------------------
// Kernel 1: headwise QKV projection (4x4 blocks) + gate GEMVs. bf16 outputs.
// ---------------------------------------------------------------------------
__global__ __launch_bounds__(256) void k_proj(
    const float* __restrict__ x,
    const float* __restrict__ wq, const float* __restrict__ wk, const float* __restrict__ wv,
    const float* __restrict__ wsi, const float* __restrict__ bi,
    const float* __restrict__ wsf, const float* __restrict__ bf,
    unsigned short* __restrict__ qb, unsigned short* __restrict__ kb,
    unsigned short* __restrict__ vb, float* __restrict__ ig, float* __restrict__ lsf)
{
  const int row = blockIdx.x;          // b*SS + s
  const int b   = row >> 11;
  const int s   = row & (SS-1);
  const int g   = threadIdx.x;         // qkv head 0..255

  const float4 xv = *(const float4*)(x + (size_t)row*DD + (g<<2));

  const int h   = g >> 6;
  const int dh0 = (g & 63) << 2;
  const size_t qi = ((size_t)(b*NHH + h)*SS + s)*DHH + dh0;

  {
    const float4 w0 = *(const float4*)(wq + g*16 + 0);
    const float4 w1 = *(const float4*)(wq + g*16 + 4);
    const float4 w2 = *(const float4*)(wq + g*16 + 8);
    const float4 w3 = *(const float4*)(wq + g*16 + 12);
    ushort4 r;
    r.x = f2b(w0.x*xv.x + w0.y*xv.y + w0.z*xv.z + w0.w*xv.w);
    r.y = f2b(w1.x*xv.x + w1.y*xv.y + w1.z*xv.z + w1.w*xv.w);
    r.z = f2b(w2.x*xv.x + w2.y*xv.y + w2.z*xv.z + w2.w*xv.w);
    r.w = f2b(w3.x*xv.x + w3.y*xv.y + w3.z*xv.z + w3.w*xv.w);
    *(ushort4*)(qb + qi) = r;
  }
  {
    const float4 w0 = *(const float4*)(wk + g*16 + 0);
    const float4 w1 = *(const float4*)(wk + g*16 + 4);
    const float4 w2 = *(const float4*)(wk + g*16 + 8);
    const float4 w3 = *(const float4*)(wk + g*16 + 12);
    ushort4 r;
    r.x = f2b(0.0625f*(w0.x*xv.x + w0.y*xv.y + w0.z*xv.z + w0.w*xv.w));
    r.y = f2b(0.0625f*(w1.x*xv.x + w1.y*xv.y + w1.z*xv.z + w1.w*xv.w));
    r.z = f2b(0.0625f*(w2.x*xv.x + w2.y*xv.y + w2.z*xv.z + w2.w*xv.w));
    r.w = f2b(0.0625f*(w3.x*xv.x + w3.y*xv.y + w3.z*xv.z + w3.w*xv.w));
    *(ushort4*)(kb + qi) = r;
  }
  {
    const float4 w0 = *(const float4*)(wv + g*16 + 0);
    const float4 w1 = *(const float4*)(wv + g*16 + 4);
    const float4 w2 = *(const float4*)(wv + g*16 + 8);
    const float4 w3 = *(const float4*)(wv + g*16 + 12);
    ushort4 r;
    r.x = f2b(w0.x*xv.x + w0.y*xv.y + w0.z*xv.z + w0.w*xv.w);
    r.y = f2b(w1.x*xv.x + w1.y*xv.y + w1.z*xv.z + w1.w*xv.w);
    r.z = f2b(w2.x*xv.x + w2.y*xv.y + w2.z*xv.z + w2.w*xv.w);
    r.w = f2b(w3.x*xv.x + w3.y*xv.y + w3.z*xv.z + w3.w*xv.w);
    *(ushort4*)(vb + qi) = r;
  }

  float pi[4], pf[4];
  const int c = g << 2;
  #pragma unroll
  for (int n=0;n<4;n++) {
    const float4 a0 = *(const float4*)(wsi + n*DD + c);
    pi[n] = a0.x*xv.x + a0.y*xv.y + a0.z*xv.z + a0.w*xv.w;
    const float4 b0 = *(const float4*)(wsf + n*DD + c);
    pf[n] = b0.x*xv.x + b0.y*xv.y + b0.z*xv.z + b0.w*xv.w;
  }
  #pragma unroll
  for (int off=32; off>0; off>>=1) {
    #pragma unroll
    for (int n=0;n<4;n++) {
      pi[n] += __shfl_down(pi[n], off);
      pf[n] += __shfl_down(pf[n], off);
    }
  }
  __shared__ float red[4][8];
  const int lane = g & 63, wid = g >> 6;
  if (lane == 0) {
    #pragma unroll
    for (int n=0;n<4;n++) { red[wid][n] = pi[n]; red[wid][4+n] = pf[n]; }
  }
  __syncthreads();
  if (g < 4) {
    const int n = g;
    float ti = red[0][n]+red[1][n]+red[2][n]+red[3][n] + bi[n];
    float tf = red[0][4+n]+red[1][4+n]+red[2][4+n]+red[3][4+n] + bf[n];
    ig[(size_t)(b*NHH+n)*SS + s] = ti;
    float ls = (tf >= 0.f) ? -log1pf(expf(-tf)) : (tf - log1pf(expf(tf)));
    lsf[(size_t)(b*NHH+n)*SS + s] = ls;
  }
}

// ---------------------------------------------------------------------------
// Kernel 2: per-(b,head) scan.
// ---------------------------------------------------------------------------
__global__ __launch_bounds__(256) void k_scan(
    const float* __restrict__ ig, const float* __restrict__ lsf,
    float* __restrict__ aa, float* __restrict__ mm, float* __restrict__ flr)
{
  const int bh = blockIdx.x;
  const int tid = threadIdx.x;
  const float* igp = ig + (size_t)bh*SS;
  const float* lsp = lsf + (size_t)bh*SS;
  float* ap = aa + (size_t)bh*SS;
  float* mp = mm + (size_t)bh*SS;
  float* fp = flr + (size_t)bh*SS;

  __shared__ float sb[256];
  const int base = tid*8;
  float l[8], c[8];
  #pragma unroll
  for (int j=0;j<8;j++) l[j] = lsp[base+j];
  c[0] = l[0];
  #pragma unroll
  for (int j=1;j<8;j++) c[j] = c[j-1] + l[j];

  sb[tid] = c[7];
  __syncthreads();
  for (int off=1; off<256; off<<=1) {
    float v = sb[tid];
    float u = (tid>=off) ? sb[tid-off] : 0.f;
    __syncthreads();
    sb[tid] = v + u;
    __syncthreads();
  }
  const float exs = (tid==0) ? 0.f : sb[tid-1];

  float cs[8], a8[8], mx[8];
  #pragma unroll
  for (int j=0;j<8;j++) { cs[j] = exs + c[j]; a8[j] = igp[base+j] - cs[j]; }
  mx[0] = a8[0];
  #pragma unroll
  for (int j=1;j<8;j++) mx[j] = fmaxf(mx[j-1], a8[j]);

  __syncthreads();
  sb[tid] = mx[7];
  __syncthreads();
  for (int off=1; off<256; off<<=1) {
    float v = sb[tid];
    float u = (tid>=off) ? sb[tid-off] : -INFINITY;
    __syncthreads();
    sb[tid] = fmaxf(v, u);
    __syncthreads();
  }
  const float exm = (tid==0) ? -INFINITY : sb[tid-1];

  #pragma unroll
  for (int j=0;j<8;j++) {
    float mmx = fmaxf(exm, mx[j]);
    ap[base+j] = a8[j];
    mp[base+j] = mmx;
    fp[base+j] = expf(-(cs[j] + mmx));
  }
}

// ---------------------------------------------------------------------------
// Kernel 3: transpose V bf16 [bh][s][d] -> Vt [bh][d][s].
// ---------------------------------------------------------------------------
__global__ __launch_bounds__(256) void k_vt(
    const unsigned short* __restrict__ vb, unsigned short* __restrict__ vt)
{
  __shared__ unsigned short tile[64][72];
  const int bh = blockIdx.x, st = blockIdx.y, dt = blockIdx.z;
  const int s0 = st*64, d0 = dt*64;
  const unsigned short* src = vb + ((size_t)bh*SS + s0)*DHH + d0;
  #pragma unroll
  for (int j=0;j<2;j++){
    int f = threadIdx.x + j*256;           // 0..511
    int r = f>>3, c = (f&7)*8;
    *(uint4*)&tile[r][c] = *(const uint4*)(src + (size_t)r*DHH + c);
  }
  __syncthreads();
  unsigned short* dst = vt + ((size_t)bh*DHH + d0)*SS + s0;
  #pragma unroll
  for (int j=0;j<2;j++){
    int f = threadIdx.x + j*256;
    int dr = f>>3, sc = (f&7)*8;
    unsigned short tmp[8];
    #pragma unroll
    for (int i=0;i<8;i++) tmp[i] = tile[sc+i][dr];
    *(uint4*)(dst + (size_t)dr*SS + sc) = *(uint4*)tmp;
  }
}

// ---------------------------------------------------------------------------
// Kernel 4: MFMA attention, counted-vmcnt pipeline.
// 256 blocks = 8 bh (XCD pin, bid&7) x 32 q-tiles of 64 rows (deepest first).
// 8 waves: wr=wid>>2 (32-row band), wc=wid&3 (16-col QKT strip / 64-d slice).
// LDS: K dbuf 2x32KB + Vt dbuf 2x32KB + W 8KB + red 3KB = 142336 B.
// Per k-tile: issue stage(kt+1) [8 gload_lds + 1 av load = 9 vmem ops/wave]
//  -> s_waitcnt vmcnt(9) ; s_barrier      (stage(kt) landed; kt+1 in flight)
//  -> QK(kt) ; W phase ; lgkmcnt(0) ; s_barrier
//  -> PV(kt) ; lgkmcnt(0) ; s_barrier     (V/W safe to overwrite next iter)
// Never drains vmcnt to 0 in the loop. Last iter re-stages kt (clamp) to
// keep the count exact.
// ---------------------------------------------------------------------------
__global__ __launch_bounds__(512, 2) void k_attn(
    const unsigned short* __restrict__ qb, const unsigned short* __restrict__ kb,
    const unsigned short* __restrict__ vt,
    const float* __restrict__ ab, const float* __restrict__ mb,
    const float* __restrict__ flr, const float* __restrict__ ln_w,
    float* __restrict__ out)
{
  extern __shared__ char sm[];
  char* smK = sm;                          // 2 x 32768
  char* smV = sm + 65536;                  // 2 x 32768
  char* smW = sm + 131072;                 // 8192 (64 rows x 128B, swizzled)
  float* smRed = (float*)(sm + 139264);    // 64 x 4
  float* smS1  = smRed + 256;              // 64 x 4
  float* smS2  = smS1 + 256;               // 64 x 4

  const int bid = blockIdx.x;
  const int bh  = bid & 7;                 // XCD pin
  const int rt  = 31 - (bid >> 3);         // deepest q-tiles dispatch first
  const int s0  = rt * 64;
  const int nkt = rt + 1;

  const int tid  = threadIdx.x;
  const int lane = tid & 63;
  const int wid  = tid >> 6;
  const int wr   = wid >> 2;               // 0..1
  const int wc   = wid & 3;                // 0..3
  const int l15  = lane & 15, lg = lane >> 4;
  const int bhoff = bh * SS;
  const int b = bh >> 2, h = bh & 3;

  const char* kbh = (const char*)(kb + (size_t)bh*SS*DHH);   // rows of 512B
  const char* vth = (const char*)(vt + (size_t)bh*DHH*SS);   // d-rows of 4096B

  const int trel = 16*wc + l15;            // QKT col within k-tile, 0..63

  // ---- prologue: stage tile 0 into buf 0, load av(0), Q frags, m ----
  {
    #pragma unroll
    for (int i=0;i<4;i++) {
      int f = tid + i*512;
      int r = f >> 5, ch = f & 31;
      gload_lds16(smK + (size_t)f*16, kbh + (size_t)r*512 + ((ch ^ (r & 7))<<4));
    }
    #pragma unroll
    for (int i=0;i<4;i++) {
      int f = tid + i*512;
      int d = f >> 3, ch = f & 7;
      gload_lds16(smV + (size_t)f*16, vth + (size_t)d*4096 + ((ch ^ (d & 7))<<4));
    }
  }
  float avC = ab[bhoff + trel];

  short8 qf[2][8];
  {
    const unsigned short* qp = qb + ((size_t)bh*SS + s0 + 32*wr)*DHH;
    #pragma unroll
    for (int mt=0; mt<2; ++mt)
      #pragma unroll
      for (int ks=0; ks<8; ++ks)
        qf[mt][ks] = *(const short8*)(qp + (16*mt + l15)*DHH + 32*ks + 8*lg);
  }
  float mrow[2][4];
  #pragma unroll
  for (int mt=0; mt<2; ++mt)
    #pragma unroll
    for (int rr=0; rr<4; ++rr)
      mrow[mt][rr] = mb[bhoff + s0 + 32*wr + 16*mt + 4*lg + rr];

  f32x4 oacc[2][4];
  #pragma unroll
  for (int mt=0; mt<2; ++mt)
    #pragma unroll
    for (int nt=0; nt<4; ++nt)
      oacc[mt][nt] = (f32x4){0.f,0.f,0.f,0.f};
  float denp[2][4] = {{0.f,0.f,0.f,0.f},{0.f,0.f,0.f,0.f}};

  for (int kt = 0; kt < nkt; ++kt) {
    const int t0 = kt*64;

    // ---- 1. issue stage(kt+1) (clamped) + av(kt+1): 9 vmem ops/wave ----
    const int tn = (kt+1 < nkt) ? (kt+1) : kt;
    {
      const char* kg = kbh + (size_t)tn*64*512;
      char* kl = smK + ((kt+1)&1)*32768;
      #pragma unroll
      for (int i=0;i<4;i++) {
        int f = tid + i*512;
        int r = f >> 5, ch = f & 31;
        gload_lds16(kl + (size_t)f*16, kg + (size_t)r*512 + ((ch ^ (r & 7))<<4));
      }
      const char* vg = vth + (size_t)tn*128;
      char* vl = smV + ((kt+1)&1)*32768;
      #pragma unroll
      for (int i=0;i<4;i++) {
        int f = tid + i*512;
        int d = f >> 3, ch = f & 7;
        gload_lds16(vl + (size_t)f*16, vg + (size_t)d*4096 + ((ch ^ (d & 7))<<4));
      }
    }
    float avN = ab[bhoff + tn*64 + trel];

    // ---- 2. wait ONLY for stage(kt) (9 newest stay in flight), sync ----
    asm volatile("s_waitcnt vmcnt(9)" ::: "memory");
    __builtin_amdgcn_s_barrier();
    asm volatile("" ::: "memory");

    const char* kl = smK + (kt&1)*32768;
    const char* vl = smV + (kt&1)*32768;

    // ---- 3. QK^T (K pre-scaled by 1/16): 32 rows x 16 cols per wave ----
    f32x4 sacc[2];
    sacc[0] = (f32x4){0.f,0.f,0.f,0.f};
    sacc[1] = (f32x4){0.f,0.f,0.f,0.f};
    __builtin_amdgcn_s_setprio(1);
    #pragma unroll
    for (int ks=0; ks<8; ++ks) {
      short8 kf = *(const short8*)(kl + (size_t)trel*512 + (((4*ks + lg) ^ (trel & 7))<<4));
      sacc[0] = __builtin_amdgcn_mfma_f32_16x16x32_bf16(qf[0][ks], kf, sacc[0], 0, 0, 0);
      sacc[1] = __builtin_amdgcn_mfma_f32_16x16x32_bf16(qf[1][ks], kf, sacc[1], 0, 0, 0);
    }
    __builtin_amdgcn_s_setprio(0);

    // ---- 4. W = mask * qk * exp(a[t]-m[s]) -> bf16 swizzled LDS ----
    {
      const bool lastt = (kt == nkt-1);
      #pragma unroll
      for (int mt=0; mt<2; ++mt) {
        #pragma unroll
        for (int rr=0; rr<4; ++rr) {
          const int srel = 32*wr + 16*mt + 4*lg + rr;
          float wv = sacc[mt][rr] * __expf(avC - mrow[mt][rr]);
          if (lastt && (t0 + trel > s0 + srel)) wv = 0.f;
          denp[mt][rr] += wv;
          *(unsigned short*)(smW + (size_t)srel*128 + (((trel >> 3) ^ (srel & 7))<<4)
                              + ((trel & 7)<<1)) = f2b(wv);
        }
      }
    }
    avC = avN;
    asm volatile("s_waitcnt lgkmcnt(0)" ::: "memory");
    __builtin_amdgcn_s_barrier();
    asm volatile("" ::: "memory");

    // ---- 5. PV: oacc += W @ V ; 32 rows x 64-d slice per wave ----
    #pragma unroll
    for (int kst=0; kst<2; ++kst) {
      short8 wf0, wf1;
      { const int sr = 32*wr + l15;
        wf0 = *(const short8*)(smW + (size_t)sr*128 + (((4*kst+lg)^(sr&7))<<4)); }
      { const int sr = 32*wr + 16 + l15;
        wf1 = *(const short8*)(smW + (size_t)sr*128 + (((4*kst+lg)^(sr&7))<<4)); }
      __builtin_amdgcn_s_setprio(1);
      #pragma unroll
      for (int nt=0; nt<4; ++nt) {
        const int d = 64*wc + 16*nt + l15;
        short8 vf = *(const short8*)(vl + (size_t)d*128 + (((4*kst+lg)^(d&7))<<4));
        oacc[0][nt] = __builtin_amdgcn_mfma_f32_16x16x32_bf16(wf0, vf, oacc[0][nt], 0, 0, 0);
        oacc[1][nt] = __builtin_amdgcn_mfma_f32_16x16x32_bf16(wf1, vf, oacc[1][nt], 0, 0, 0);
      }
      __builtin_amdgcn_s_setprio(0);
    }

    // ---- 6. PV reads done -> next iter may overwrite V/W ----
    asm volatile("s_waitcnt lgkmcnt(0)" ::: "memory");
    __builtin_amdgcn_s_barrier();
    asm volatile("" ::: "memory");
  }

  // ---- epilogue: den reduce (lanes then wc-waves), normalizer, LN, write ----
  #pragma unroll
  for (int mt=0; mt<2; ++mt)
    #pragma unroll
    for (int rr=0; rr<4; ++rr) {
      float v = denp[mt][rr];
      v += __shfl_xor(v, 1); v += __shfl_xor(v, 2);
      v += __shfl_xor(v, 4); v += __shfl_xor(v, 8);
      if (l15 == 0) smRed[(32*wr + 16*mt + 4*lg + rr)*4 + wc] = v;
    }
  __syncthreads();

  float inv[2][4];
  #pragma unroll
  for (int mt=0; mt<2; ++mt)
    #pragma unroll
    for (int rr=0; rr<4; ++rr) {
      const int srel = 32*wr + 16*mt + 4*lg + rr;
      float dsum = smRed[srel*4+0] + smRed[srel*4+1] + smRed[srel*4+2] + smRed[srel*4+3];
      float f = flr[bhoff + s0 + srel];
      inv[mt][rr] = 1.f / (fmaxf(fabsf(dsum), f) + 1e-8f);
    }

  float s1p[2][4] = {{0,0,0,0},{0,0,0,0}}, s2p[2][4] = {{0,0,0,0},{0,0,0,0}};
  #pragma unroll
  for (int mt=0; mt<2; ++mt)
    #pragma unroll
    for (int nt=0; nt<4; ++nt)
      #pragma unroll
      for (int rr=0; rr<4; ++rr) {
        float v = oacc[mt][nt][rr] * inv[mt][rr];
        oacc[mt][nt][rr] = v;
        s1p[mt][rr] += v;
        s2p[mt][rr] += v*v;
      }
  #pragma unroll
  for (int mt=0; mt<2; ++mt)
    #pragma unroll
    for (int rr=0; rr<4; ++rr) {
      float a = s1p[mt][rr], q = s2p[mt][rr];
      a += __shfl_xor(a, 1); a += __shfl_xor(a, 2);
      a += __shfl_xor(a, 4); a += __shfl_xor(a, 8);
      q += __shfl_xor(q, 1); q += __shfl_xor(q, 2);
      q += __shfl_xor(q, 4); q += __shfl_xor(q, 8);
      if (l15 == 0) {
        const int srel = 32*wr + 16*mt + 4*lg + rr;
        smS1[srel*4 + wc] = a;
        smS2[srel*4 + wc] = q;
      }
    }
  __syncthreads();

  float g4[4];
  #pragma unroll
  for (int nt=0; nt<4; ++nt) g4[nt] = 1.f + ln_w[h*DHH + 64*wc + 16*nt + l15];

  #pragma unroll
  for (int mt=0; mt<2; ++mt)
    #pragma unroll
    for (int rr=0; rr<4; ++rr) {
      const int srel = 32*wr + 16*mt + 4*lg + rr;
      const float ms = smS1[srel*4+0] + smS1[srel*4+1] + smS1[srel*4+2] + smS1[srel*4+3];
      const float sq = smS2[srel*4+0] + smS2[srel*4+1] + smS2[srel*4+2] + smS2[srel*4+3];
      const float mean = ms * (1.f/DHH);
      const float var  = sq * (1.f/DHH) - mean*mean;
      const float rstd = rsqrtf(var + 1e-5f);
      float* op = out + ((size_t)(b*SS + s0 + srel))*DD + h*DHH;
      #pragma unroll
      for (int nt=0; nt<4; ++nt)
        op[64*wc + 16*nt + l15] = (oacc[mt][nt][rr] - mean)*rstd*g4[nt];
    }
}

// ---------------------------------------------------------------------------
extern "C" void kernel_launch(void* const* d_in, const int* in_sizes, int n_in,
                              void* d_out, int out_size, void* d_ws, size_t ws_size,
                              hipStream_t stream) {
  (void)in_sizes; (void)n_in; (void)out_size; (void)ws_size;
  const float* x    = (const float*)d_in[0];
  const float* wq   = (const float*)d_in[1];
  const float* wk   = (const float*)d_in[2];
  const float* wv   = (const float*)d_in[3];
  const float* wi   = (const float*)d_in[4];
  const float* bi   = (const float*)d_in[5];
  const float* wf   = (const float*)d_in[6];
  const float* bf   = (const float*)d_in[7];
  const float* ln_w = (const float*)d_in[8];
  float* out = (float*)d_out;
  char* ws = (char*)d_ws;

  unsigned short* QB = (unsigned short*)(ws + QB_OFF);
  unsigned short* KB = (unsigned short*)(ws + KB_OFF);
  unsigned short* VT = (unsigned short*)(ws + VT_OFF);
  unsigned short* VB = (unsigned short*)(ws + VB_OFF);
  float* IG  = (float*)(ws + IG_OFF);
  float* LSF = (float*)(ws + LSF_OFF);
  float* AA  = (float*)(ws + AA_OFF);
  float* MM  = (float*)(ws + MM_OFF);
  float* FLR = (float*)(ws + FLR_OFF);
  float* WSI = (float*)(ws + WSI_OFF);
  float* WSF = (float*)(ws + WSF_OFF);

  k_gw<<<32, 256, 0, stream>>>(wi, wf, WSI, WSF);
  k_proj<<<BB*SS, 256, 0, stream>>>(x, wq, wk, wv, WSI, bi, WSF, bf, QB, KB, VB, IG, LSF);
  k_scan<<<BHH, 256, 0, stream>>>(IG, LSF, AA, MM, FLR);
  k_vt<<<dim3(BHH, SS/64, DHH/64), 256, 0, stream>>>(VB, VT);
  k_attn<<<256, 512, 142336, stream>>>(QB, KB, VT, AA, MM, FLR, ln_w, out);
}

// Round 8
// 98.384 us; speedup vs baseline: 2.3381x; 1.0034x over previous
//
#include <hip/hip_runtime.h>
#include <math.h>

// ---------------------------------------------------------------------------
// mLSTM cell, MFMA bf16. Round 8: paired-band k_attn (block p = q-bands
// [32p,32p+32) and [2016-32p,2048-32p) sharing one k-sweep -> nktA+nktB ~= 33
// active-wave-tiles for EVERY block: exact balance, no atomics, K/V staging
// amortized over 64 rows in the overlap region). 2 barriers/tile (top barrier
// carries lgkmcnt(0) so PV reads retire before next stage/W writes).
// k_proj: 4 rows/block, weights register-preloaded (L2 traffic / 4).
// ---------------------------------------------------------------------------

#define BB   2
#define SS   2048
#define DD   1024
#define NHH  4
#define DHH  256
#define BHH  (BB*NHH)

// Workspace byte offsets (total ~32.5 MB)
#define QB_OFF   ((size_t)0)
#define KB_OFF   ((size_t)8  << 20)
#define VT_OFF   ((size_t)16 << 20)
#define VB_OFF   ((size_t)24 << 20)
#define IG_OFF   ((size_t)32 << 20)
#define LSF_OFF  (IG_OFF  + ((size_t)64<<10))
#define AA_OFF   (LSF_OFF + ((size_t)64<<10))
#define MM_OFF   (AA_OFF  + ((size_t)64<<10))
#define FLR_OFF  (MM_OFF  + ((size_t)64<<10))
#define WSI_OFF  (FLR_OFF + ((size_t)64<<10))
#define WSF_OFF  (WSI_OFF + ((size_t)32<<10))

typedef __attribute__((ext_vector_type(8))) short short8;   // 8 bf16 (4 VGPR)
typedef __attribute__((ext_vector_type(4))) float f32x4;

typedef const __attribute__((address_space(1))) unsigned int* gas1_u32;
typedef __attribute__((address_space(3))) unsigned int* las3_u32;

__device__ __forceinline__ unsigned short f2b(float f) {
  union { float f; unsigned int u; } v; v.f = f;
  unsigned int r = (v.u + 0x7FFFu + ((v.u >> 16) & 1u)) >> 16;
  return (unsigned short)r;
}

__device__ __forceinline__ void gload_lds16(void* lds, const void* g) {
  __builtin_amdgcn_global_load_lds((gas1_u32)g, (las3_u32)lds, 16, 0, 0);
}

__device__ __forceinline__ float dot4(float4 a, float4 b) {
  return a.x*b.x + a.y*b.y + a.z*b.z + a.w*b.w;
}

// ---------------------------------------------------------------------------
// Kernel 0: gate weight pre-sum: wsum[n][c] = sum of 3 D-segments.
// ---------------------------------------------------------------------------
__global__ __launch_bounds__(256) void k_gw(
    const float* __restrict__ wi, const float* __restrict__ wf,
    float* __restrict__ wsi, float* __restrict__ wsf)
{
  const int idx = blockIdx.x*256 + threadIdx.x;   // 0..8191
  const int n = idx >> 10, c = idx & 1023;
  wsi[idx] = wi[n*3*DD + c] + wi[n*3*DD + DD + c] + wi[n*3*DD + 2*DD + c];
  wsf[idx] = wf[n*3*DD + c] + wf[n*3*DD + DD + c] + wf[n*3*DD + 2*DD + c];
}

// ---------------------------------------------------------------------------
// Kernel 1: headwise QKV projection + gate GEMVs, 4 rows/block.
// Weights register-preloaded once per block (amortized 4x).
// ---------------------------------------------------------------------------
__global__ __launch_bounds__(256) void k_proj(
    const float* __restrict__ x,
    const float* __restrict__ wq, const float* __restrict__ wk, const float* __restrict__ wv,
    const float* __restrict__ wsi, const float* __restrict__ bi,
    const float* __restrict__ wsf, const float* __restrict__ bf,
    unsigned short* __restrict__ qb, unsigned short* __restrict__ kb,
    unsigned short* __restrict__ vb, float* __restrict__ ig, float* __restrict__ lsf)
{
  const int rb = blockIdx.x;           // 0..1023, 4 rows each
  const int g  = threadIdx.x;          // qkv head 0..255
  const int h   = g >> 6;
  const int dh0 = (g & 63) << 2;
  const int c   = g << 2;
  const int lane = g & 63, wid = g >> 6;

  // preload all weights this thread ever needs
  const float4 q0 = *(const float4*)(wq + g*16 + 0);
  const float4 q1 = *(const float4*)(wq + g*16 + 4);
  const float4 q2 = *(const float4*)(wq + g*16 + 8);
  const float4 q3 = *(const float4*)(wq + g*16 + 12);
  const float4 k0 = *(const float4*)(wk + g*16 + 0);
  const float4 k1 = *(const float4*)(wk + g*16 + 4);
  const float4 k2 = *(const float4*)(wk + g*16 + 8);
  const float4 k3 = *(const float4*)(wk + g*16 + 12);
  const float4 v0 = *(const float4*)(wv + g*16 + 0);
  const float4 v1 = *(const float4*)(wv + g*16 + 4);
  const float4 v2 = *(const float4*)(wv + g*16 + 8);
  const float4 v3 = *(const float4*)(wv + g*16 + 12);
  const float4 gi0 = *(const float4*)(wsi + 0*DD + c);
  const float4 gi1 = *(const float4*)(wsi + 1*DD + c);
  const float4 gi2 = *(const float4*)(wsi + 2*DD + c);
  const float4 gi3 = *(const float4*)(wsi + 3*DD + c);
  const float4 gf0 = *(const float4*)(wsf + 0*DD + c);
  const float4 gf1 = *(const float4*)(wsf + 1*DD + c);
  const float4 gf2 = *(const float4*)(wsf + 2*DD + c);
  const float4 gf3 = *(const float4*)(wsf + 3*DD + c);

  __shared__ float redI[4][4][4];   // [row][n][wid]
  __shared__ float redF[4][4][4];

  #pragma unroll
  for (int r4 = 0; r4 < 4; ++r4) {
    const int row = rb*4 + r4;
    const int b = row >> 11, s = row & (SS-1);
    const float4 xv = *(const float4*)(x + (size_t)row*DD + c);
    const size_t qi = ((size_t)(b*NHH + h)*SS + s)*DHH + dh0;

    ushort4 r;
    r.x = f2b(dot4(q0,xv)); r.y = f2b(dot4(q1,xv));
    r.z = f2b(dot4(q2,xv)); r.w = f2b(dot4(q3,xv));
    *(ushort4*)(qb + qi) = r;
    r.x = f2b(0.0625f*dot4(k0,xv)); r.y = f2b(0.0625f*dot4(k1,xv));
    r.z = f2b(0.0625f*dot4(k2,xv)); r.w = f2b(0.0625f*dot4(k3,xv));
    *(ushort4*)(kb + qi) = r;
    r.x = f2b(dot4(v0,xv)); r.y = f2b(dot4(v1,xv));
    r.z = f2b(dot4(v2,xv)); r.w = f2b(dot4(v3,xv));
    *(ushort4*)(vb + qi) = r;

    float pi0 = dot4(gi0,xv), pi1 = dot4(gi1,xv), pi2 = dot4(gi2,xv), pi3 = dot4(gi3,xv);
    float pf0 = dot4(gf0,xv), pf1 = dot4(gf1,xv), pf2 = dot4(gf2,xv), pf3 = dot4(gf3,xv);
    #pragma unroll
    for (int off=32; off>0; off>>=1) {
      pi0 += __shfl_down(pi0, off); pi1 += __shfl_down(pi1, off);
      pi2 += __shfl_down(pi2, off); pi3 += __shfl_down(pi3, off);
      pf0 += __shfl_down(pf0, off); pf1 += __shfl_down(pf1, off);
      pf2 += __shfl_down(pf2, off); pf3 += __shfl_down(pf3, off);
    }
    if (lane == 0) {
      redI[r4][0][wid] = pi0; redI[r4][1][wid] = pi1;
      redI[r4][2][wid] = pi2; redI[r4][3][wid] = pi3;
      redF[r4][0][wid] = pf0; redF[r4][1][wid] = pf1;
      redF[r4][2][wid] = pf2; redF[r4][3][wid] = pf3;
    }
  }
  __syncthreads();
  if (g < 16) {
    const int r4 = g >> 2, n = g & 3;
    const int row = rb*4 + r4;
    const int b = row >> 11, s = row & (SS-1);
    float ti = redI[r4][n][0]+redI[r4][n][1]+redI[r4][n][2]+redI[r4][n][3] + bi[n];
    float tf = redF[r4][n][0]+redF[r4][n][1]+redF[r4][n][2]+redF[r4][n][3] + bf[n];
    ig[(size_t)(b*NHH+n)*SS + s] = ti;
    float ls = (tf >= 0.f) ? -log1pf(expf(-tf)) : (tf - log1pf(expf(tf)));
    lsf[(size_t)(b*NHH+n)*SS + s] = ls;
  }
}

// ---------------------------------------------------------------------------
// Kernel 2: per-(b,head) scan.
// ---------------------------------------------------------------------------
__global__ __launch_bounds__(256) void k_scan(
    const float* __restrict__ ig, const float* __restrict__ lsf,
    float* __restrict__ aa, float* __restrict__ mm, float* __restrict__ flr)
{
  const int bh = blockIdx.x;
  const int tid = threadIdx.x;
  const float* igp = ig + (size_t)bh*SS;
  const float* lsp = lsf + (size_t)bh*SS;
  float* ap = aa + (size_t)bh*SS;
  float* mp = mm + (size_t)bh*SS;
  float* fp = flr + (size_t)bh*SS;

  __shared__ float sb[256];
  const int base = tid*8;
  float l[8], c[8];
  #pragma unroll
  for (int j=0;j<8;j++) l[j] = lsp[base+j];
  c[0] = l[0];
  #pragma unroll
  for (int j=1;j<8;j++) c[j] = c[j-1] + l[j];

  sb[tid] = c[7];
  __syncthreads();
  for (int off=1; off<256; off<<=1) {
    float v = sb[tid];
    float u = (tid>=off) ? sb[tid-off] : 0.f;
    __syncthreads();
    sb[tid] = v + u;
    __syncthreads();
  }
  const float exs = (tid==0) ? 0.f : sb[tid-1];

  float cs[8], a8[8], mx[8];
  #pragma unroll
  for (int j=0;j<8;j++) { cs[j] = exs + c[j]; a8[j] = igp[base+j] - cs[j]; }
  mx[0] = a8[0];
  #pragma unroll
  for (int j=1;j<8;j++) mx[j] = fmaxf(mx[j-1], a8[j]);

  __syncthreads();
  sb[tid] = mx[7];
  __syncthreads();
  for (int off=1; off<256; off<<=1) {
    float v = sb[tid];
    float u = (tid>=off) ? sb[tid-off] : -INFINITY;
    __syncthreads();
    sb[tid] = fmaxf(v, u);
    __syncthreads();
  }
  const float exm = (tid==0) ? -INFINITY : sb[tid-1];

  #pragma unroll
  for (int j=0;j<8;j++) {
    float mmx = fmaxf(exm, mx[j]);
    ap[base+j] = a8[j];
    mp[base+j] = mmx;
    fp[base+j] = expf(-(cs[j] + mmx));
  }
}

// ---------------------------------------------------------------------------
// Kernel 3: transpose V bf16 [bh][s][d] -> Vt [bh][d][s].
// ---------------------------------------------------------------------------
__global__ __launch_bounds__(256) void k_vt(
    const unsigned short* __restrict__ vb, unsigned short* __restrict__ vt)
{
  __shared__ unsigned short tile[64][72];
  const int bh = blockIdx.x, st = blockIdx.y, dt = blockIdx.z;
  const int s0 = st*64, d0 = dt*64;
  const unsigned short* src = vb + ((size_t)bh*SS + s0)*DHH + d0;
  #pragma unroll
  for (int j=0;j<2;j++){
    int f = threadIdx.x + j*256;           // 0..511
    int r = f>>3, c = (f&7)*8;
    *(uint4*)&tile[r][c] = *(const uint4*)(src + (size_t)r*DHH + c);
  }
  __syncthreads();
  unsigned short* dst = vt + ((size_t)bh*DHH + d0)*SS + s0;
  #pragma unroll
  for (int j=0;j<2;j++){
    int f = threadIdx.x + j*256;
    int dr = f>>3, sc = (f&7)*8;
    unsigned short tmp[8];
    #pragma unroll
    for (int i=0;i<8;i++) tmp[i] = tile[sc+i][dr];
    *(uint4*)(dst + (size_t)dr*SS + sc) = *(uint4*)tmp;
  }
}

// ---------------------------------------------------------------------------
// Kernel 4: MFMA attention, paired-band blocks, counted pipeline.
// 256 blocks = 8 bh (XCD pin, bid&7) x 32 pairs. Pair p: band A rows
// [32p,32p+32), band B rows [2016-32p,2048-32p); one shared k-sweep of
// nktB tiles; band A active while kt < nktA. nktA+nktB ~= 33 for all p.
// 8 waves: wr=wid>>2 -> band, wc=wid&3 -> 16-col QKT strip / 64-d PV slice.
// Per tile: [vmcnt(0)+lgkm(0); barrier] [issue stage(kt+1) other buf]
// [QK] [W phase] [lgkm(0); barrier] [PV]. 2 barriers, stage flies ~1 tile.
// LDS: K dbuf 2x32KB + Vt dbuf 2x32KB + W 8KB + red 3KB = 142336 B.
// ---------------------------------------------------------------------------
__global__ __launch_bounds__(512, 2) void k_attn(
    const unsigned short* __restrict__ qb, const unsigned short* __restrict__ kb,
    const unsigned short* __restrict__ vt,
    const float* __restrict__ ab, const float* __restrict__ mb,
    const float* __restrict__ flr, const float* __restrict__ ln_w,
    float* __restrict__ out)
{
  extern __shared__ char sm[];
  char* smK = sm;                          // 2 x 32768
  char* smV = sm + 65536;                  // 2 x 32768
  char* smW = sm + 131072;                 // 8192 (64 rows x 128B, swizzled)
  float* smRed = (float*)(sm + 139264);    // 64 x 4
  float* smS1  = smRed + 256;              // 64 x 4
  float* smS2  = smS1 + 256;               // 64 x 4

  const int bid = blockIdx.x;
  const int bh  = bid & 7;                 // XCD pin
  const int p   = bid >> 3;                // pair 0..31
  const int s0A = 32*p;
  const int s0B = 2016 - 32*p;
  const int nktA = (32*p + 95) >> 6;       // band-A causal tile count
  const int nktB = (2111 - 32*p) >> 6;     // band-B causal tile count (17..32)

  const int tid  = threadIdx.x;
  const int lane = tid & 63;
  const int wid  = tid >> 6;
  const int wr   = wid >> 2;               // 0 = band A, 1 = band B
  const int wc   = wid & 3;                // col strip / d slice
  const int l15  = lane & 15, lg = lane >> 4;
  const int bhoff = bh * SS;
  const int b = bh >> 2, h = bh & 3;

  const int s0w  = wr ? s0B : s0A;
  const int nktW = wr ? nktB : nktA;

  const char* kbh = (const char*)(kb + (size_t)bh*SS*DHH);   // rows of 512B
  const char* vth = (const char*)(vt + (size_t)bh*DHH*SS);   // d-rows of 4096B
  const int trel = 16*wc + l15;            // QKT col within k-tile, 0..63

  // ---- prologue: stage tile 0 into buf 0, av(0), Q frags, m ----
  {
    #pragma unroll
    for (int i=0;i<4;i++) {
      int f = tid + i*512;
      int r = f >> 5, ch = f & 31;
      gload_lds16(smK + (size_t)f*16, kbh + (size_t)r*512 + ((ch ^ (r & 7))<<4));
    }
    #pragma unroll
    for (int i=0;i<4;i++) {
      int f = tid + i*512;
      int d = f >> 3, ch = f & 7;
      gload_lds16(smV + (size_t)f*16, vth + (size_t)d*4096 + ((ch ^ (d & 7))<<4));
    }
  }
  float avC = ab[bhoff + trel];

  short8 qf[2][8];
  {
    const unsigned short* qp = qb + ((size_t)bh*SS + s0w)*DHH;
    #pragma unroll
    for (int mt=0; mt<2; ++mt)
      #pragma unroll
      for (int ks=0; ks<8; ++ks)
        qf[mt][ks] = *(const short8*)(qp + (16*mt + l15)*DHH + 32*ks + 8*lg);
  }
  float mrow[2][4];
  #pragma unroll
  for (int mt=0; mt<2; ++mt)
    #pragma unroll
    for (int rr=0; rr<4; ++rr)
      mrow[mt][rr] = mb[bhoff + s0w + 16*mt + 4*lg + rr];

  f32x4 oacc[2][4];
  #pragma unroll
  for (int mt=0; mt<2; ++mt)
    #pragma unroll
    for (int nt=0; nt<4; ++nt)
      oacc[mt][nt] = (f32x4){0.f,0.f,0.f,0.f};
  float denp[2][4] = {{0.f,0.f,0.f,0.f},{0.f,0.f,0.f,0.f}};

  for (int kt = 0; kt < nktB; ++kt) {
    const int t0 = kt*64;

    // ---- 1. stage(kt) landed (issued a full tile ago) + all prev-tile LDS
    //         reads retired on every wave -> safe to write stage/W below ----
    asm volatile("s_waitcnt vmcnt(0) lgkmcnt(0)" ::: "memory");
    __builtin_amdgcn_s_barrier();
    asm volatile("" ::: "memory");

    // ---- 2. issue stage(kt+1) (clamped) into other buffer + av(kt+1) ----
    const int tn = (kt+1 < nktB) ? (kt+1) : kt;
    {
      const char* kg = kbh + (size_t)tn*64*512;
      char* kl = smK + ((kt+1)&1)*32768;
      #pragma unroll
      for (int i=0;i<4;i++) {
        int f = tid + i*512;
        int r = f >> 5, ch = f & 31;
        gload_lds16(kl + (size_t)f*16, kg + (size_t)r*512 + ((ch ^ (r & 7))<<4));
      }
      const char* vg = vth + (size_t)tn*128;
      char* vl = smV + ((kt+1)&1)*32768;
      #pragma unroll
      for (int i=0;i<4;i++) {
        int f = tid + i*512;
        int d = f >> 3, ch = f & 7;
        gload_lds16(vl + (size_t)f*16, vg + (size_t)d*4096 + ((ch ^ (d & 7))<<4));
      }
    }
    float avN = ab[bhoff + tn*64 + trel];

    const char* kl = smK + (kt&1)*32768;
    const char* vl = smV + (kt&1)*32768;
    const bool act = (kt < nktW);

    if (act) {
      // ---- 3. QK^T (K pre-scaled by 1/16): 32 band rows x 16 cols ----
      f32x4 sacc[2];
      sacc[0] = (f32x4){0.f,0.f,0.f,0.f};
      sacc[1] = (f32x4){0.f,0.f,0.f,0.f};
      __builtin_amdgcn_s_setprio(1);
      #pragma unroll
      for (int ks=0; ks<8; ++ks) {
        short8 kf = *(const short8*)(kl + (size_t)trel*512 + (((4*ks + lg) ^ (trel & 7))<<4));
        sacc[0] = __builtin_amdgcn_mfma_f32_16x16x32_bf16(qf[0][ks], kf, sacc[0], 0, 0, 0);
        sacc[1] = __builtin_amdgcn_mfma_f32_16x16x32_bf16(qf[1][ks], kf, sacc[1], 0, 0, 0);
      }
      __builtin_amdgcn_s_setprio(0);

      // ---- 4. W = mask * qk * exp(a[t]-m[s]) -> bf16 swizzled LDS ----
      const bool lastt = (kt == nktW-1);
      #pragma unroll
      for (int mt=0; mt<2; ++mt) {
        #pragma unroll
        for (int rr=0; rr<4; ++rr) {
          const int rib  = 16*mt + 4*lg + rr;       // row in band
          const int srel = 32*wr + rib;             // W tile row
          float wv = sacc[mt][rr] * __expf(avC - mrow[mt][rr]);
          if (lastt && (t0 + trel > s0w + rib)) wv = 0.f;
          denp[mt][rr] += wv;
          *(unsigned short*)(smW + (size_t)srel*128 + (((trel >> 3) ^ (srel & 7))<<4)
                              + ((trel & 7)<<1)) = f2b(wv);
        }
      }
    }
    avC = avN;

    // ---- 5. W visible to the band's 4 waves ----
    asm volatile("s_waitcnt lgkmcnt(0)" ::: "memory");
    __builtin_amdgcn_s_barrier();
    asm volatile("" ::: "memory");

    if (act) {
      // ---- 6. PV: oacc += W @ V ; 32 band rows x 64-d slice ----
      #pragma unroll
      for (int kst=0; kst<2; ++kst) {
        short8 wf0, wf1;
        { const int sr = 32*wr + l15;
          wf0 = *(const short8*)(smW + (size_t)sr*128 + (((4*kst+lg)^(sr&7))<<4)); }
        { const int sr = 32*wr + 16 + l15;
          wf1 = *(const short8*)(smW + (size_t)sr*128 + (((4*kst+lg)^(sr&7))<<4)); }
        __builtin_amdgcn_s_setprio(1);
        #pragma unroll
        for (int nt=0; nt<4; ++nt) {
          const int d = 64*wc + 16*nt + l15;
          short8 vf = *(const short8*)(vl + (size_t)d*128 + (((4*kst+lg)^(d&7))<<4));
          oacc[0][nt] = __builtin_amdgcn_mfma_f32_16x16x32_bf16(wf0, vf, oacc[0][nt], 0, 0, 0);
          oacc[1][nt] = __builtin_amdgcn_mfma_f32_16x16x32_bf16(wf1, vf, oacc[1][nt], 0, 0, 0);
        }
        __builtin_amdgcn_s_setprio(0);
      }
    }
  }

  // ---- epilogue: den reduce (lanes then wc-waves), normalizer, LN, write ----
  __syncthreads();
  #pragma unroll
  for (int mt=0; mt<2; ++mt)
    #pragma unroll
    for (int rr=0; rr<4; ++rr) {
      float v = denp[mt][rr];
      v += __shfl_xor(v, 1); v += __shfl_xor(v, 2);
      v += __shfl_xor(v, 4); v += __shfl_xor(v, 8);
      if (l15 == 0) smRed[(32*wr + 16*mt + 4*lg + rr)*4 + wc] = v;
    }
  __syncthreads();

  float inv[2][4];
  #pragma unroll
  for (int mt=0; mt<2; ++mt)
    #pragma unroll
    for (int rr=0; rr<4; ++rr) {
      const int rib  = 16*mt + 4*lg + rr;
      const int srel = 32*wr + rib;
      float dsum = smRed[srel*4+0] + smRed[srel*4+1] + smRed[srel*4+2] + smRed[srel*4+3];
      float f = flr[bhoff + s0w + rib];
      inv[mt][rr] = 1.f / (fmaxf(fabsf(dsum), f) + 1e-8f);
    }

  float s1p[2][4] = {{0,0,0,0},{0,0,0,0}}, s2p[2][4] = {{0,0,0,0},{0,0,0,0}};
  #pragma unroll
  for (int mt=0; mt<2; ++mt)
    #pragma unroll
    for (int nt=0; nt<4; ++nt)
      #pragma unroll
      for (int rr=0; rr<4; ++rr) {
        float v = oacc[mt][nt][rr] * inv[mt][rr];
        oacc[mt][nt][rr] = v;
        s1p[mt][rr] += v;
        s2p[mt][rr] += v*v;
      }
  #pragma unroll
  for (int mt=0; mt<2; ++mt)
    #pragma unroll
    for (int rr=0; rr<4; ++rr) {
      float a = s1p[mt][rr], q = s2p[mt][rr];
      a += __shfl_xor(a, 1); a += __shfl_xor(a, 2);
      a += __shfl_xor(a, 4); a += __shfl_xor(a, 8);
      q += __shfl_xor(q, 1); q += __shfl_xor(q, 2);
      q += __shfl_xor(q, 4); q += __shfl_xor(q, 8);
      if (l15 == 0) {
        const int srel = 32*wr + 16*mt + 4*lg + rr;
        smS1[srel*4 + wc] = a;
        smS2[srel*4 + wc] = q;
      }
    }
  __syncthreads();

  float g4[4];
  #pragma unroll
  for (int nt=0; nt<4; ++nt) g4[nt] = 1.f + ln_w[h*DHH + 64*wc + 16*nt + l15];

  #pragma unroll
  for (int mt=0; mt<2; ++mt)
    #pragma unroll
    for (int rr=0; rr<4; ++rr) {
      const int rib  = 16*mt + 4*lg + rr;
      const int srel = 32*wr + rib;
      const float ms = smS1[srel*4+0] + smS1[srel*4+1] + smS1[srel*4+2] + smS1[srel*4+3];
      const float sq = smS2[srel*4+0] + smS2[srel*4+1] + smS2[srel*4+2] + smS2[srel*4+3];
      const float mean = ms * (1.f/DHH);
      const float var  = sq * (1.f/DHH) - mean*mean;
      const float rstd = rsqrtf(var + 1e-5f);
      float* op = out + ((size_t)(b*SS + s0w + rib))*DD + h*DHH;
      #pragma unroll
      for (int nt=0; nt<4; ++nt)
        op[64*wc + 16*nt + l15] = (oacc[mt][nt][rr] - mean)*rstd*g4[nt];
    }
}

// ---------------------------------------------------------------------------
extern "C" void kernel_launch(void* const* d_in, const int* in_sizes, int n_in,
                              void* d_out, int out_size, void* d_ws, size_t ws_size,
                              hipStream_t stream) {
  (void)in_sizes; (void)n_in; (void)out_size; (void)ws_size;
  const float* x    = (const float*)d_in[0];
  const float* wq   = (const float*)d_in[1];
  const float* wk   = (const float*)d_in[2];
  const float* wv   = (const float*)d_in[3];
  const float* wi   = (const float*)d_in[4];
  const float* bi   = (const float*)d_in[5];
  const float* wf   = (const float*)d_in[6];
  const float* bf   = (const float*)d_in[7];
  const float* ln_w = (const float*)d_in[8];
  float* out = (float*)d_out;
  char* ws = (char*)d_ws;

  unsigned short* QB = (unsigned short*)(ws + QB_OFF);
  unsigned short* KB = (unsigned short*)(ws + KB_OFF);
  unsigned short* VT = (unsigned short*)(ws + VT_OFF);
  unsigned short* VB = (unsigned short*)(ws + VB_OFF);
  float* IG  = (float*)(ws + IG_OFF);
  float* LSF = (float*)(ws + LSF_OFF);
  float* AA  = (float*)(ws + AA_OFF);
  float* MM  = (float*)(ws + MM_OFF);
  float* FLR = (float*)(ws + FLR_OFF);
  float* WSI = (float*)(ws + WSI_OFF);
  float* WSF = (float*)(ws + WSF_OFF);

  k_gw<<<32, 256, 0, stream>>>(wi, wf, WSI, WSF);
  k_proj<<<1024, 256, 0, stream>>>(x, wq, wk, wv, WSI, bi, WSF, bf, QB, KB, VB, IG, LSF);
  k_scan<<<BHH, 256, 0, stream>>>(IG, LSF, AA, MM, FLR);
  k_vt<<<dim3(BHH, SS/64, DHH/64), 256, 0, stream>>>(VB, VT);
  k_attn<<<256, 512, 142336, stream>>>(QB, KB, VT, AA, MM, FLR, ln_w, out);
}